// Round 7
// baseline (3929.320 us; speedup 1.0000x reference)
//
#include <hip/hip_runtime.h>
#include <hip/hip_bf16.h>
#include <stdint.h>

#define NTILES 4
#define DMODEL 1024
#define DFF    4096
#define NTOK   16384
#define JPX    9          // job slots per XCD (8*9=72 >= max 68 jobs)

typedef __bf16 bf16x8 __attribute__((ext_vector_type(8)));
typedef float  f32x4  __attribute__((ext_vector_type(4)));

__device__ __forceinline__ uint16_t f2bf(float f) {
    union { float f; uint32_t u; } v; v.f = f;
    uint32_t u = v.u;
    uint32_t r = (u + 0x7fffu + ((u >> 16) & 1u)) >> 16;
    return (uint16_t)r;
}

#define STG(gptr, ldsptr) __builtin_amdgcn_global_load_lds( \
    (__attribute__((address_space(1))) void*)(gptr), \
    (__attribute__((address_space(3))) void*)(ldsptr), 16, 0, 0)

// ---------------- fused Wup fp32->bf16 convert + signature partial sums ----------------
__global__ void k_convup(const float* __restrict__ Wup, uint16_t* __restrict__ wupb,
                         double* __restrict__ partial) {
    int e = blockIdx.y, fb = blockIdx.x, tid = threadIdx.x;
    const float* src = Wup + (size_t)e * DFF * DMODEL + (size_t)fb * 16 * DMODEL + tid * 4;
    uint16_t*    dst = wupb + (size_t)e * DFF * DMODEL + (size_t)fb * 16 * DMODEL + tid * 4;
    double s0 = 0, s1 = 0, s2 = 0, s3 = 0;
    #pragma unroll 4
    for (int i = 0; i < 16; ++i) {
        float4 v = *(const float4*)(src + (size_t)i * DMODEL);
        ushort4 h;
        h.x = f2bf(v.x); h.y = f2bf(v.y); h.z = f2bf(v.z); h.w = f2bf(v.w);
        *(ushort4*)(dst + (size_t)i * DMODEL) = h;
        s0 += v.x; s1 += v.y; s2 += v.z; s3 += v.w;
    }
    int c = tid * 4;
    double* p = partial + ((size_t)e * DMODEL + c) * 256 + fb;
    p[0 * 256] = s0; p[1 * 256] = s1; p[2 * 256] = s2; p[3 * 256] = s3;
}

// signature finalize (parallel) + zero expert counts
__global__ void k_sig_final(const double* __restrict__ partial, float* __restrict__ sig,
                            int* __restrict__ counts) {
    int b = blockIdx.x;
    int sub = threadIdx.x >> 5;
    int l32 = threadIdx.x & 31;
    int idx = b * 8 + sub;
    const double* p = partial + (size_t)idx * 256 + l32;
    double s = 0.0;
    #pragma unroll
    for (int i = 0; i < 8; ++i) s += p[i * 32];
    #pragma unroll
    for (int off = 16; off; off >>= 1) s += __shfl_xor(s, off);
    if (l32 == 0) sig[idx] = (s > 0.0) ? 1.0f : ((s < 0.0) ? -1.0f : 0.0f);
    if (b == 0 && threadIdx.x < NTILES) counts[threadIdx.x] = 0;
}

// ---------------- routing ----------------
__global__ void __launch_bounds__(256) k_route(const float* __restrict__ x,
                                               const float* __restrict__ sig,
                                               uint16_t* __restrict__ xb,
                                               float* __restrict__ gate_out,
                                               int* __restrict__ counts,
                                               int* __restrict__ perm) {
    __shared__ float sl[NTILES * DMODEL];
    for (int i = threadIdx.x; i < NTILES * DMODEL; i += 256) sl[i] = sig[i];
    __syncthreads();
    int wave = threadIdx.x >> 6, lane = threadIdx.x & 63;
    int tok = blockIdx.x * 4 + wave;
    const float* xr = x + (size_t)tok * DMODEL;
    float sc[NTILES] = {0.f, 0.f, 0.f, 0.f};
    for (int q = 0; q < 4; ++q) {
        int c = q * 256 + lane * 4;
        float4 xv = *(const float4*)(xr + c);
        #pragma unroll
        for (int t = 0; t < NTILES; ++t) {
            const float* st = sl + t * DMODEL + c;
            sc[t] += xv.x * st[0] + xv.y * st[1] + xv.z * st[2] + xv.w * st[3];
        }
        ushort4 h;
        h.x = f2bf(xv.x); h.y = f2bf(xv.y); h.z = f2bf(xv.z); h.w = f2bf(xv.w);
        *(ushort4*)(xb + (size_t)tok * DMODEL + c) = h;
    }
    #pragma unroll
    for (int t = 0; t < NTILES; ++t)
        for (int off = 32; off; off >>= 1) sc[t] += __shfl_xor(sc[t], off);
    int w = 0; float best = sc[0];
    if (sc[1] > best) { best = sc[1]; w = 1; }
    if (sc[2] > best) { best = sc[2]; w = 2; }
    if (sc[3] > best) { best = sc[3]; w = 3; }
    if (lane < NTILES) gate_out[(size_t)tok * NTILES + lane] = (lane == w) ? 1.0f : 0.0f;
    if (lane == 0) {
        int pos = atomicAdd(&counts[w], 1);
        perm[w * NTOK + pos] = tok;
    }
}

// ---------------- fp32 -> bf16 convert (Wdown) ----------------
__global__ void k_conv(const float* __restrict__ src, uint16_t* __restrict__ dst, int n4) {
    int stride = gridDim.x * blockDim.x;
    for (int i = blockIdx.x * blockDim.x + threadIdx.x; i < n4; i += stride) {
        float4 v = *(const float4*)(src + (size_t)i * 4);
        ushort4 h;
        h.x = f2bf(v.x); h.y = f2bf(v.y); h.z = f2bf(v.z); h.w = f2bf(v.w);
        *(ushort4*)(dst + (size_t)i * 4) = h;
    }
}

// ---------------- grouped NT GEMM: 256x256 tile, K-tile=32, 2-slot dbuf ----------------
// Occupancy-first: 64 KB LDS + <=128 VGPR -> 2 blocks/CU; cross-block implicit
// overlap (m97/m114 mechanism) hides vmcnt/barrier stalls.
// 1-D grid, XCD-contiguous jobs: xcd=bid&7 owns jobs [xcd*JPX, ...); x fastest
// so A-tile partners are co-resident on one XCD's L2 (T1).
// Per K-tile: {4 STG (tile t+1) | vmcnt(4) | barrier | 12 ds_read | lgkm(0) |
// 32 MFMA | barrier}.  Slot layout + swizzle identical to R5/R6 (verified).
#define SLOTB 32768

template <int K, bool UP, int NX>
__global__ void __launch_bounds__(512, 4)
k_ffn7(const uint16_t* __restrict__ A, const uint16_t* __restrict__ Bw,
       const int* __restrict__ counts, const int* __restrict__ perm,
       uint16_t* __restrict__ hid_out, float* __restrict__ out) {
    constexpr int NOUT = UP ? DFF : DMODEL;
    constexpr int NT = K / 32;
    extern __shared__ char smem[];

    // ---- XCD-contiguous job decode ----
    const int bid = blockIdx.x;
    const int xcd = bid & 7;
    const int kk  = bid >> 3;
    const int j   = xcd * JPX + kk / NX;
    const int xt  = kk % NX;

    const int c0 = counts[0], c1 = counts[1], c2 = counts[2], c3 = counts[3];
    const int n0 = (c0 + 255) >> 8, n1 = (c1 + 255) >> 8, n2 = (c2 + 255) >> 8,
              n3 = (c3 + 255) >> 8;
    int e, yt, cnt, cofs;
    if (j < n0)                     { e = 0; yt = j;                cnt = c0; cofs = 0; }
    else if (j < n0 + n1)           { e = 1; yt = j - n0;           cnt = c1; cofs = c0; }
    else if (j < n0 + n1 + n2)      { e = 2; yt = j - n0 - n1;      cnt = c2; cofs = c0 + c1; }
    else if (j < n0 + n1 + n2 + n3) { e = 3; yt = j - n0 - n1 - n2; cnt = c3; cofs = c0 + c1 + c2; }
    else return;
    const int base = yt * 256;
    const int bn0 = xt * 256;

    const int tid = threadIdx.x;
    const int lane = tid & 63, wid = tid >> 6;
    const int wr = wid >> 2, wc = wid & 3;
    const int* permE = perm + e * NTOK;

    // ---- staging thread decode (verified R5/R6): line qs, slot tid&7
    const int qs = tid >> 3;
    const int ls = (tid & 7) ^ (qs & 7);
    const int us = ls >> 2, gs = ls & 3;

    const uint16_t* bP[2];
    #pragma unroll
    for (int jj = 0; jj < 2; ++jj)
        bP[jj] = Bw + ((size_t)e * NOUT + bn0 + jj * 128 + 2 * qs + us) * K + gs * 8;

    const uint16_t* aP[2];
    #pragma unroll
    for (int jj = 0; jj < 2; ++jj) {
        int rowj = jj * 128 + 2 * qs + us;
        if constexpr (UP) {
            int rr = base + rowj;
            int tok = permE[(rr < cnt) ? rr : base];
            aP[jj] = A + (size_t)tok * K + gs * 8;
        } else {
            aP[jj] = A + (size_t)(cofs + base + rowj) * K + gs * 8;
        }
    }

    char* stA = smem + wid * 1024;
    char* stB = smem + 16384 + wid * 1024;

    // ---- fragment read offsets (verified R5/R6)
    const int r0a = wr * 128 + (lane & 15);
    const int qa  = r0a >> 1;
    const int sa  = (((r0a & 1) << 2) | (lane >> 4)) ^ (qa & 7);
    const int Aoff = qa * 128 + sa * 16;
    const int r0b = wc * 64 + (lane & 15);
    const int qb  = r0b >> 1;
    const int sb  = (((r0b & 1) << 2) | (lane >> 4)) ^ (qb & 7);
    const int Boff = 16384 + qb * 128 + sb * 16;

    f32x4 acc[8][4];
    #pragma unroll
    for (int m = 0; m < 8; ++m)
        #pragma unroll
        for (int n = 0; n < 4; ++n) acc[m][n] = (f32x4){0.f, 0.f, 0.f, 0.f};

    // prologue: stage tile 0 -> slot 0
    STG(aP[0], stA);
    STG(aP[1], stA + 8192);
    STG(bP[0], stB);
    STG(bP[1], stB + 8192);

    #pragma unroll 1
    for (int t = 0; t < NT; ++t) {
        const char* sp = smem + (t & 1) * SLOTB;
        const int so = ((t & 1) ^ 1) * SLOTB;
        const bool pre = (t + 1) < NT;

        if (pre) {
            STG(aP[0] + (t + 1) * 32, stA + so);
            STG(aP[1] + (t + 1) * 32, stA + so + 8192);
            STG(bP[0] + (t + 1) * 32, stB + so);
            STG(bP[1] + (t + 1) * 32, stB + so + 8192);
            asm volatile("s_waitcnt vmcnt(4)" ::: "memory");
        } else {
            asm volatile("s_waitcnt vmcnt(0)" ::: "memory");
        }
        __builtin_amdgcn_sched_barrier(0);
        __builtin_amdgcn_s_barrier();

        bf16x8 aF[8], bF[4];
        #pragma unroll
        for (int m = 0; m < 8; ++m) aF[m] = *(const bf16x8*)(sp + Aoff + m * 1024);
        #pragma unroll
        for (int n = 0; n < 4; ++n) bF[n] = *(const bf16x8*)(sp + Boff + n * 1024);
        asm volatile("s_waitcnt lgkmcnt(0)" ::: "memory");
        __builtin_amdgcn_sched_barrier(0);
        __builtin_amdgcn_s_setprio(1);
        #pragma unroll
        for (int m = 0; m < 8; ++m)
            #pragma unroll
            for (int n = 0; n < 4; ++n)
                acc[m][n] = __builtin_amdgcn_mfma_f32_16x16x32_bf16(aF[m], bF[n], acc[m][n], 0, 0, 0);
        __builtin_amdgcn_s_setprio(0);
        __builtin_amdgcn_s_barrier();
    }

    // epilogue: r = wr*128 + m*16 + (lane>>4)*4 + i, c = wc*64 + n*16 + (lane&15)
    #pragma unroll
    for (int m = 0; m < 8; ++m) {
        #pragma unroll
        for (int i = 0; i < 4; ++i) {
            int r  = wr * 128 + m * 16 + (lane >> 4) * 4 + i;
            int rr = base + r;
            if (rr < cnt) {
                if constexpr (UP) {
                    uint16_t* hr = hid_out + (size_t)(cofs + rr) * DFF + bn0 + wc * 64;
                    #pragma unroll
                    for (int n = 0; n < 4; ++n) {
                        float v = acc[m][n][i];
                        v = v > 0.f ? v : 0.f;
                        hr[n * 16 + (lane & 15)] = f2bf(v);
                    }
                } else {
                    float* orow = out + (size_t)permE[rr] * DMODEL + bn0 + wc * 64;
                    #pragma unroll
                    for (int n = 0; n < 4; ++n)
                        orow[n * 16 + (lane & 15)] = acc[m][n][i];
                }
            }
        }
    }
}

extern "C" void kernel_launch(void* const* d_in, const int* in_sizes, int n_in,
                              void* d_out, int out_size, void* d_ws, size_t ws_size,
                              hipStream_t stream) {
    const float* x     = (const float*)d_in[0];
    const float* Wup   = (const float*)d_in[1];
    const float* Wdown = (const float*)d_in[2];
    float* out  = (float*)d_out;
    float* gate = out + (size_t)NTOK * DMODEL;

    char* ws = (char*)d_ws;
    size_t off = 0;
    auto alloc = [&](size_t bytes) -> void* {
        void* p = ws + off;
        off += (bytes + 255) & ~(size_t)255;
        return p;
    };
    int*      counts  = (int*)alloc(NTILES * sizeof(int));
    float*    sig     = (float*)alloc((size_t)NTILES * DMODEL * sizeof(float));
    double*   partial = (double*)alloc((size_t)NTILES * DMODEL * 256 * sizeof(double));
    int*      perm    = (int*)alloc((size_t)NTILES * NTOK * sizeof(int));
    uint16_t* xb      = (uint16_t*)alloc((size_t)NTOK * DMODEL * 2);
    uint16_t* wupb    = (uint16_t*)alloc((size_t)NTILES * DFF * DMODEL * 2);
    uint16_t* wdownb  = (uint16_t*)alloc((size_t)NTILES * DMODEL * DFF * 2);
    uint16_t* hidden  = (uint16_t*)alloc(((size_t)NTOK + 1024) * DFF * 2);
    if (off > ws_size) return;

    hipFuncSetAttribute((const void*)&k_ffn7<DMODEL, true, DFF / 256>,
                        hipFuncAttributeMaxDynamicSharedMemorySize, 2 * SLOTB);
    hipFuncSetAttribute((const void*)&k_ffn7<DFF, false, DMODEL / 256>,
                        hipFuncAttributeMaxDynamicSharedMemorySize, 2 * SLOTB);

    hipLaunchKernelGGL(k_convup, dim3(256, 4), dim3(256), 0, stream, Wup, wupb, partial);
    hipLaunchKernelGGL(k_sig_final, dim3(512), dim3(256), 0, stream, partial, sig, counts);
    hipLaunchKernelGGL(k_route, dim3(NTOK / 4), dim3(256), 0, stream,
                       x, sig, xb, gate, counts, perm);
    hipLaunchKernelGGL(k_conv, dim3(2048), dim3(256), 0, stream,
                       Wdown, wdownb, NTILES * DMODEL * DFF / 4);
    hipLaunchKernelGGL((k_ffn7<DMODEL, true, DFF / 256>), dim3(8 * JPX * (DFF / 256)),
                       dim3(512), 2 * SLOTB, stream, xb, wupb, counts, perm, hidden, nullptr);
    hipLaunchKernelGGL((k_ffn7<DFF, false, DMODEL / 256>), dim3(8 * JPX * (DMODEL / 256)),
                       dim3(512), 2 * SLOTB, stream, hidden, wdownb, counts, perm, nullptr, out);
}

// Round 8
// 633.035 us; speedup vs baseline: 6.2071x; 6.2071x over previous
//
#include <hip/hip_runtime.h>
#include <hip/hip_bf16.h>
#include <stdint.h>

#define NTILES 4
#define DMODEL 1024
#define DFF    4096
#define NTOK   16384

typedef __bf16 bf16x8 __attribute__((ext_vector_type(8)));
typedef float  f32x4  __attribute__((ext_vector_type(4)));

__device__ __forceinline__ uint16_t f2bf(float f) {
    union { float f; uint32_t u; } v; v.f = f;
    uint32_t u = v.u;
    uint32_t r = (u + 0x7fffu + ((u >> 16) & 1u)) >> 16;
    return (uint16_t)r;
}

#define STG(gptr, ldsoff) __builtin_amdgcn_global_load_lds( \
    (__attribute__((address_space(1))) void*)(gptr), \
    (__attribute__((address_space(3))) void*)(smem + (ldsoff)), 16, 0, 0)

// ---------------- fused converts: Wup->bf16 (+signature partials) AND Wdown->bf16 ----------------
// grid (512, 4): fb<256 -> Wup rows fb*16..+15 (with column partial sums);
//                fb>=256 -> Wdown flat chunk (fb-256)*16384 elements.
__global__ void k_convert(const float* __restrict__ Wup, const float* __restrict__ Wdown,
                          uint16_t* __restrict__ wupb, uint16_t* __restrict__ wdownb,
                          double* __restrict__ partial) {
    int e = blockIdx.y, fb = blockIdx.x, tid = threadIdx.x;
    if (fb < 256) {
        const float* src = Wup + (size_t)e * DFF * DMODEL + (size_t)fb * 16 * DMODEL + tid * 4;
        uint16_t*    dst = wupb + (size_t)e * DFF * DMODEL + (size_t)fb * 16 * DMODEL + tid * 4;
        double s0 = 0, s1 = 0, s2 = 0, s3 = 0;
        #pragma unroll 4
        for (int i = 0; i < 16; ++i) {
            float4 v = *(const float4*)(src + (size_t)i * DMODEL);
            ushort4 h;
            h.x = f2bf(v.x); h.y = f2bf(v.y); h.z = f2bf(v.z); h.w = f2bf(v.w);
            *(ushort4*)(dst + (size_t)i * DMODEL) = h;
            s0 += v.x; s1 += v.y; s2 += v.z; s3 += v.w;
        }
        int c = tid * 4;
        double* p = partial + ((size_t)e * DMODEL + c) * 256 + fb;
        p[0 * 256] = s0; p[1 * 256] = s1; p[2 * 256] = s2; p[3 * 256] = s3;
    } else {
        int fb2 = fb - 256;
        const float* src = Wdown + (size_t)e * DMODEL * DFF + (size_t)fb2 * 16384 + tid * 4;
        uint16_t*    dst = wdownb + (size_t)e * DMODEL * DFF + (size_t)fb2 * 16384 + tid * 4;
        #pragma unroll 4
        for (int i = 0; i < 16; ++i) {
            float4 v = *(const float4*)(src + (size_t)i * 1024);
            ushort4 h;
            h.x = f2bf(v.x); h.y = f2bf(v.y); h.z = f2bf(v.z); h.w = f2bf(v.w);
            *(ushort4*)(dst + (size_t)i * 1024) = h;
        }
    }
}

// signature finalize (parallel) + zero expert counts
__global__ void k_sig_final(const double* __restrict__ partial, float* __restrict__ sig,
                            int* __restrict__ counts) {
    int b = blockIdx.x;
    int sub = threadIdx.x >> 5;
    int l32 = threadIdx.x & 31;
    int idx = b * 8 + sub;
    const double* p = partial + (size_t)idx * 256 + l32;
    double s = 0.0;
    #pragma unroll
    for (int i = 0; i < 8; ++i) s += p[i * 32];
    #pragma unroll
    for (int off = 16; off; off >>= 1) s += __shfl_xor(s, off);
    if (l32 == 0) sig[idx] = (s > 0.0) ? 1.0f : ((s < 0.0) ? -1.0f : 0.0f);
    if (b == 0 && threadIdx.x < NTILES) counts[threadIdx.x] = 0;
}

// ---------------- routing: scores, argmax, gate, xb (bf16 copy), buckets ----------------
__global__ void __launch_bounds__(256) k_route(const float* __restrict__ x,
                                               const float* __restrict__ sig,
                                               uint16_t* __restrict__ xb,
                                               float* __restrict__ gate_out,
                                               int* __restrict__ counts,
                                               int* __restrict__ perm) {
    __shared__ float sl[NTILES * DMODEL];
    for (int i = threadIdx.x; i < NTILES * DMODEL; i += 256) sl[i] = sig[i];
    __syncthreads();
    int wave = threadIdx.x >> 6, lane = threadIdx.x & 63;
    int tok = blockIdx.x * 4 + wave;
    const float* xr = x + (size_t)tok * DMODEL;
    float sc[NTILES] = {0.f, 0.f, 0.f, 0.f};
    for (int q = 0; q < 4; ++q) {
        int c = q * 256 + lane * 4;
        float4 xv = *(const float4*)(xr + c);
        #pragma unroll
        for (int t = 0; t < NTILES; ++t) {
            const float* st = sl + t * DMODEL + c;
            sc[t] += xv.x * st[0] + xv.y * st[1] + xv.z * st[2] + xv.w * st[3];
        }
        ushort4 h;
        h.x = f2bf(xv.x); h.y = f2bf(xv.y); h.z = f2bf(xv.z); h.w = f2bf(xv.w);
        *(ushort4*)(xb + (size_t)tok * DMODEL + c) = h;
    }
    #pragma unroll
    for (int t = 0; t < NTILES; ++t)
        for (int off = 32; off; off >>= 1) sc[t] += __shfl_xor(sc[t], off);
    int w = 0; float best = sc[0];
    if (sc[1] > best) { best = sc[1]; w = 1; }
    if (sc[2] > best) { best = sc[2]; w = 2; }
    if (sc[3] > best) { best = sc[3]; w = 3; }
    if (lane < NTILES) gate_out[(size_t)tok * NTILES + lane] = (lane == w) ? 1.0f : 0.0f;
    if (lane == 0) {
        int pos = atomicAdd(&counts[w], 1);
        perm[w * NTOK + pos] = tok;
    }
}

// ---------------- grouped NT GEMM (R2-exact schedule, verified 206us) ----------------
// BM=128 (tokens), BN=256 (weight rows), BK=64; 512 thr = 8 waves (2Mx4N),
// per-wave 64x64 (acc[4][4]).  LDS: 3-slot ring, slot = A[128][64] + B[256][64]
// = 48KB; 144KB total -> 1 block/CU.  2-tile lookahead, boundary vmcnt(6).
// Swizzle: phys_in_row = logical ^ ((row&7)<<4); staging sources inverse-swizzled.
// Deltas vs R2 (both verified R5-R7): UP writes hidden expert-sorted (cofs+rr);
// DOWN stages A contiguously (no perm gather), scatters out via perm.
#define SLOT 49152

template <int K, bool UP>
__global__ void __launch_bounds__(512, 2)
k_ffn2(const uint16_t* __restrict__ A, const uint16_t* __restrict__ Bw,
       const int* __restrict__ counts, const int* __restrict__ perm,
       uint16_t* __restrict__ hid_out, float* __restrict__ out) {
    constexpr int NOUT = UP ? DFF : DMODEL;
    constexpr int NT = K / 64;
    extern __shared__ char smem[];

    const int e = blockIdx.z;
    const int c0 = counts[0], c1 = counts[1], c2 = counts[2];
    const int cnt = counts[e];
    const int cofs = (e > 0 ? c0 : 0) + (e > 1 ? c1 : 0) + (e > 2 ? c2 : 0);
    const int base = blockIdx.y * 128;
    if (base >= cnt) return;
    const int bn0 = blockIdx.x * 256;
    const int tid = threadIdx.x;
    const int lane = tid & 63, wid = tid >> 6;
    const int wr = wid >> 2, wc = wid & 3;
    const int* permE = perm + e * NTOK;

    // staging source pointers (inverse-swizzled global columns)
    const uint16_t* gA[2];
    #pragma unroll
    for (int j = 0; j < 2; ++j) {
        int r  = wid * 16 + j * 8 + (lane >> 3);
        int rr = base + r;
        int c8 = (lane & 7) ^ (r & 7);
        if constexpr (UP) {
            int tok = permE[(rr < cnt) ? rr : base];
            gA[j] = A + (size_t)tok * K + c8 * 8;
        } else {
            gA[j] = A + (size_t)(cofs + rr) * K + c8 * 8;
        }
    }
    const uint16_t* gB[4];
    #pragma unroll
    for (int j = 0; j < 4; ++j) {
        int r  = wid * 32 + j * 8 + (lane >> 3);
        int c8 = (lane & 7) ^ (r & 7);
        gB[j] = Bw + ((size_t)e * NOUT + bn0 + r) * K + c8 * 8;
    }
    const int ldsA = wid * 2048;
    const int ldsB = 16384 + wid * 4096;

    const int Aoff = (wr * 64 + (lane & 15)) * 128;
    const int Boff = 16384 + (wc * 64 + (lane & 15)) * 128;
    const int inrow0 = (((lane >> 4) * 16)      ) ^ ((lane & 7) << 4);
    const int inrow1 = (64 + ((lane >> 4) * 16)) ^ ((lane & 7) << 4);

    f32x4 acc[4][4];
    #pragma unroll
    for (int m = 0; m < 4; ++m)
        #pragma unroll
        for (int n = 0; n < 4; ++n) acc[m][n] = (f32x4){0.f, 0.f, 0.f, 0.f};

    #define STAGE_TILE(S, T) do { \
        STG(gA[0] + (T) * 64, (S) * SLOT + ldsA); \
        STG(gA[1] + (T) * 64, (S) * SLOT + ldsA + 1024); \
        STG(gB[0] + (T) * 64, (S) * SLOT + ldsB); \
        STG(gB[1] + (T) * 64, (S) * SLOT + ldsB + 1024); \
        STG(gB[2] + (T) * 64, (S) * SLOT + ldsB + 2048); \
        STG(gB[3] + (T) * 64, (S) * SLOT + ldsB + 3072); \
    } while (0)
    STAGE_TILE(0, 0);
    STAGE_TILE(1, 1);
    asm volatile("s_waitcnt vmcnt(6)" ::: "memory");
    __builtin_amdgcn_sched_barrier(0);
    __builtin_amdgcn_s_barrier();

    int cs = 0;
    #pragma unroll 1
    for (int t = 0; t < NT; ++t) {
        const char* sp = smem + cs * SLOT;
        const bool pre = (t + 2) < NT;
        const int ss = (cs == 0) ? 2 : cs - 1;   // (t+2)%3

        // ---- phase 0 (kk = 0) ----
        {
            bf16x8 aF[4], bF[4];
            #pragma unroll
            for (int m = 0; m < 4; ++m) aF[m] = *(const bf16x8*)(sp + Aoff + m * 2048 + inrow0);
            #pragma unroll
            for (int n = 0; n < 4; ++n) bF[n] = *(const bf16x8*)(sp + Boff + n * 2048 + inrow0);
            if (pre) {
                STG(gA[0] + (t + 2) * 64, ss * SLOT + ldsA);
                STG(gA[1] + (t + 2) * 64, ss * SLOT + ldsA + 1024);
                STG(gB[0] + (t + 2) * 64, ss * SLOT + ldsB);
            }
            __builtin_amdgcn_s_barrier();
            asm volatile("s_waitcnt lgkmcnt(0)" ::: "memory");
            __builtin_amdgcn_sched_barrier(0);
            __builtin_amdgcn_s_setprio(1);
            #pragma unroll
            for (int m = 0; m < 4; ++m)
                #pragma unroll
                for (int n = 0; n < 4; ++n)
                    acc[m][n] = __builtin_amdgcn_mfma_f32_16x16x32_bf16(aF[m], bF[n], acc[m][n], 0, 0, 0);
            __builtin_amdgcn_s_setprio(0);
            __builtin_amdgcn_s_barrier();
        }
        // ---- phase 1 (kk = 1) ----
        {
            bf16x8 aF[4], bF[4];
            #pragma unroll
            for (int m = 0; m < 4; ++m) aF[m] = *(const bf16x8*)(sp + Aoff + m * 2048 + inrow1);
            #pragma unroll
            for (int n = 0; n < 4; ++n) bF[n] = *(const bf16x8*)(sp + Boff + n * 2048 + inrow1);
            if (pre) {
                STG(gB[1] + (t + 2) * 64, ss * SLOT + ldsB + 1024);
                STG(gB[2] + (t + 2) * 64, ss * SLOT + ldsB + 2048);
                STG(gB[3] + (t + 2) * 64, ss * SLOT + ldsB + 3072);
            }
            __builtin_amdgcn_s_barrier();
            asm volatile("s_waitcnt lgkmcnt(0)" ::: "memory");
            __builtin_amdgcn_sched_barrier(0);
            __builtin_amdgcn_s_setprio(1);
            #pragma unroll
            for (int m = 0; m < 4; ++m)
                #pragma unroll
                for (int n = 0; n < 4; ++n)
                    acc[m][n] = __builtin_amdgcn_mfma_f32_16x16x32_bf16(aF[m], bF[n], acc[m][n], 0, 0, 0);
            __builtin_amdgcn_s_setprio(0);
            if (pre) { asm volatile("s_waitcnt vmcnt(6)" ::: "memory"); }
            else     { asm volatile("s_waitcnt vmcnt(0)" ::: "memory"); }
            __builtin_amdgcn_sched_barrier(0);
            __builtin_amdgcn_s_barrier();
        }
        cs = (cs == 2) ? 0 : cs + 1;
    }

    // epilogue: r = wr*64 + m*16 + (lane>>4)*4 + i, c = wc*64 + n*16 + (lane&15)
    #pragma unroll
    for (int m = 0; m < 4; ++m) {
        #pragma unroll
        for (int i = 0; i < 4; ++i) {
            int r  = wr * 64 + m * 16 + (lane >> 4) * 4 + i;
            int rr = base + r;
            if (rr < cnt) {
                if constexpr (UP) {
                    uint16_t* hr = hid_out + (size_t)(cofs + rr) * DFF + bn0 + wc * 64;
                    #pragma unroll
                    for (int n = 0; n < 4; ++n) {
                        float v = acc[m][n][i];
                        v = v > 0.f ? v : 0.f;
                        hr[n * 16 + (lane & 15)] = f2bf(v);
                    }
                } else {
                    float* orow = out + (size_t)permE[rr] * DMODEL + bn0 + wc * 64;
                    #pragma unroll
                    for (int n = 0; n < 4; ++n)
                        orow[n * 16 + (lane & 15)] = acc[m][n][i];
                }
            }
        }
    }
}

extern "C" void kernel_launch(void* const* d_in, const int* in_sizes, int n_in,
                              void* d_out, int out_size, void* d_ws, size_t ws_size,
                              hipStream_t stream) {
    const float* x     = (const float*)d_in[0];
    const float* Wup   = (const float*)d_in[1];
    const float* Wdown = (const float*)d_in[2];
    float* out  = (float*)d_out;
    float* gate = out + (size_t)NTOK * DMODEL;

    char* ws = (char*)d_ws;
    size_t off = 0;
    auto alloc = [&](size_t bytes) -> void* {
        void* p = ws + off;
        off += (bytes + 255) & ~(size_t)255;
        return p;
    };
    int*      counts  = (int*)alloc(NTILES * sizeof(int));
    float*    sig     = (float*)alloc((size_t)NTILES * DMODEL * sizeof(float));
    double*   partial = (double*)alloc((size_t)NTILES * DMODEL * 256 * sizeof(double));
    int*      perm    = (int*)alloc((size_t)NTILES * NTOK * sizeof(int));
    uint16_t* xb      = (uint16_t*)alloc((size_t)NTOK * DMODEL * 2);
    uint16_t* wupb    = (uint16_t*)alloc((size_t)NTILES * DFF * DMODEL * 2);
    uint16_t* wdownb  = (uint16_t*)alloc((size_t)NTILES * DMODEL * DFF * 2);
    uint16_t* hidden  = (uint16_t*)alloc(((size_t)NTOK + 1024) * DFF * 2);
    if (off > ws_size) return;

    hipFuncSetAttribute((const void*)&k_ffn2<DMODEL, true>,
                        hipFuncAttributeMaxDynamicSharedMemorySize, 3 * SLOT);
    hipFuncSetAttribute((const void*)&k_ffn2<DFF, false>,
                        hipFuncAttributeMaxDynamicSharedMemorySize, 3 * SLOT);

    hipLaunchKernelGGL(k_convert, dim3(512, 4), dim3(256), 0, stream,
                       Wup, Wdown, wupb, wdownb, partial);
    hipLaunchKernelGGL(k_sig_final, dim3(512), dim3(256), 0, stream, partial, sig, counts);
    hipLaunchKernelGGL(k_route, dim3(NTOK / 4), dim3(256), 0, stream,
                       x, sig, xb, gate, counts, perm);
    hipLaunchKernelGGL((k_ffn2<DMODEL, true>), dim3(DFF / 256, NTOK / 128, NTILES),
                       dim3(512), 3 * SLOT, stream, xb, wupb, counts, perm, hidden, nullptr);
    hipLaunchKernelGGL((k_ffn2<DFF, false>), dim3(DMODEL / 256, NTOK / 128, NTILES),
                       dim3(512), 3 * SLOT, stream, hidden, wdownb, counts, perm, nullptr, out);
}